// Round 1
// baseline (271.600 us; speedup 1.0000x reference)
//
#include <hip/hip_runtime.h>
#include <float.h>

#define EMB_DIM     300
#define MAX_LEN     128
#define HIDDEN_DIM  1000
#define NUM_CLASSES 5
#define VOCAB_SZ    50000

// ---------------------------------------------------------------------------
// Kernel 1: embedding gather + masked avg/max pool.
// One block (128 threads) per batch row. Thread t owns dims {t, t+128, t+256}.
// rep layout: [B, 600] = [avg(300) | max(300)]
// ---------------------------------------------------------------------------
__global__ __launch_bounds__(128) void pool_kernel(
    const int* __restrict__ x, const int* __restrict__ lengths,
    const float* __restrict__ emb, float* __restrict__ rep)
{
    const int b   = blockIdx.x;
    const int tid = threadIdx.x;

    __shared__ int sidx[MAX_LEN];
    sidx[tid] = x[(size_t)b * MAX_LEN + tid];
    __syncthreads();

    int L = lengths[b];
    L = max(1, min(L, MAX_LEN));

    const int d0 = tid, d1 = tid + 128, d2 = tid + 256;
    const bool h2 = (d2 < EMB_DIM);

    float s0 = 0.f, s1 = 0.f, s2 = 0.f;
    float m0 = -FLT_MAX, m1 = -FLT_MAX, m2 = -FLT_MAX;

    for (int t = 0; t < L; ++t) {
        int idx = sidx[t];
        idx = max(0, min(idx, VOCAB_SZ - 1));   // safety clamp
        const float* row = emb + (size_t)idx * EMB_DIM;
        float v0 = row[d0]; s0 += v0; m0 = fmaxf(m0, v0);
        float v1 = row[d1]; s1 += v1; m1 = fmaxf(m1, v1);
        if (h2) { float v2 = row[d2]; s2 += v2; m2 = fmaxf(m2, v2); }
    }

    const float inv = 1.0f / (float)L;
    float* rb = rep + (size_t)b * (2 * EMB_DIM);
    rb[d0] = s0 * inv; rb[EMB_DIM + d0] = m0;
    rb[d1] = s1 * inv; rb[EMB_DIM + d1] = m1;
    if (h2) { rb[d2] = s2 * inv; rb[EMB_DIM + d2] = m2; }
}

// ---------------------------------------------------------------------------
// Kernel 2: hidden = relu(rep @ W1 + b1).  fp32 tiled GEMM.
// M=B, K=600, N=1000. 64x64 block tile, BK=8, 256 threads, 4x4 microtile.
// LDS pad +4 keeps float4 alignment and breaks the k-major write conflict.
// ---------------------------------------------------------------------------
#define BM 64
#define BN 64
#define BK 8
#define LDP 4

__global__ __launch_bounds__(256) void gemm1_relu(
    const float* __restrict__ A,   // [M, 600]
    const float* __restrict__ W,   // [600, 1000]
    const float* __restrict__ bias,// [1000]
    float* __restrict__ H,         // [M, 1000]
    int M)
{
    const int N = HIDDEN_DIM, K = 2 * EMB_DIM;
    const int bn = blockIdx.x * BN;
    const int bm = blockIdx.y * BM;

    __shared__ float As[BK][BM + LDP];
    __shared__ float Bs[BK][BN + LDP];

    const int tid = threadIdx.x;
    const int tc  = tid & 15;    // 0..15 -> output col group
    const int tr  = tid >> 4;    // 0..15 -> output row group

    float acc[4][4] = {};

    for (int k0 = 0; k0 < K; k0 += BK) {
        // A tile: 64x8 = 512 elems, 2 per thread. k = e&7 -> 8-float bursts.
        #pragma unroll
        for (int i = 0; i < 2; ++i) {
            int e = tid + i * 256;
            int m = e >> 3;
            int k = e & 7;
            int gm = bm + m;
            As[k][m] = (gm < M) ? A[(size_t)gm * K + k0 + k] : 0.f;
        }
        // B tile: 8x64 = 512 elems, coalesced over n.
        #pragma unroll
        for (int i = 0; i < 2; ++i) {
            int e = tid + i * 256;
            int k = e >> 6;
            int n = e & 63;
            int gn = bn + n;
            Bs[k][n] = (gn < N) ? W[(size_t)(k0 + k) * N + gn] : 0.f;
        }
        __syncthreads();

        #pragma unroll
        for (int k = 0; k < BK; ++k) {
            float4 a4 = *(const float4*)&As[k][tr * 4];
            float4 b4 = *(const float4*)&Bs[k][tc * 4];
            float av[4] = {a4.x, a4.y, a4.z, a4.w};
            float bv[4] = {b4.x, b4.y, b4.z, b4.w};
            #pragma unroll
            for (int i = 0; i < 4; ++i)
                #pragma unroll
                for (int j = 0; j < 4; ++j)
                    acc[i][j] += av[i] * bv[j];
        }
        __syncthreads();
    }

    #pragma unroll
    for (int i = 0; i < 4; ++i) {
        int m = bm + tr * 4 + i;
        if (m >= M) continue;
        #pragma unroll
        for (int j = 0; j < 4; ++j) {
            int n = bn + tc * 4 + j;
            if (n < N) {
                float v = acc[i][j] + bias[n];
                H[(size_t)m * N + n] = fmaxf(v, 0.f);
            }
        }
    }
}

// ---------------------------------------------------------------------------
// Kernel 3: logits = hidden @ W2 + b2.  One wave per batch row.
// ---------------------------------------------------------------------------
__global__ __launch_bounds__(64) void gemm2_kernel(
    const float* __restrict__ H,   // [B, 1000]
    const float* __restrict__ W2,  // [1000, 5]
    const float* __restrict__ b2,  // [5]
    float* __restrict__ out)       // [B, 5]
{
    const int b    = blockIdx.x;
    const int lane = threadIdx.x;
    const float* hr = H + (size_t)b * HIDDEN_DIM;

    float acc[NUM_CLASSES] = {0.f, 0.f, 0.f, 0.f, 0.f};
    for (int k = lane; k < HIDDEN_DIM; k += 64) {
        float h = hr[k];
        const float* w = W2 + (size_t)k * NUM_CLASSES;
        #pragma unroll
        for (int c = 0; c < NUM_CLASSES; ++c) acc[c] += h * w[c];
    }
    #pragma unroll
    for (int off = 32; off > 0; off >>= 1) {
        #pragma unroll
        for (int c = 0; c < NUM_CLASSES; ++c)
            acc[c] += __shfl_down(acc[c], off, 64);
    }
    if (lane == 0) {
        #pragma unroll
        for (int c = 0; c < NUM_CLASSES; ++c)
            out[(size_t)b * NUM_CLASSES + c] = acc[c] + b2[c];
    }
}

// ---------------------------------------------------------------------------
extern "C" void kernel_launch(void* const* d_in, const int* in_sizes, int n_in,
                              void* d_out, int out_size, void* d_ws, size_t ws_size,
                              hipStream_t stream)
{
    const int*   x       = (const int*)d_in[0];
    const int*   lengths = (const int*)d_in[1];
    const float* emb     = (const float*)d_in[2];
    const float* W1      = (const float*)d_in[3];
    const float* b1      = (const float*)d_in[4];
    const float* W2      = (const float*)d_in[5];
    const float* b2      = (const float*)d_in[6];
    float*       out     = (float*)d_out;

    const int B = in_sizes[1];           // 4096

    float* rep    = (float*)d_ws;                      // [B, 600]
    float* hidden = rep + (size_t)B * (2 * EMB_DIM);   // [B, 1000]

    pool_kernel<<<B, 128, 0, stream>>>(x, lengths, emb, rep);

    dim3 g1((HIDDEN_DIM + BN - 1) / BN, (B + BM - 1) / BM);
    gemm1_relu<<<g1, 256, 0, stream>>>(rep, W1, b1, hidden, B);

    gemm2_kernel<<<B, 64, 0, stream>>>(hidden, W2, b2, out);
}

// Round 2
// 168.396 us; speedup vs baseline: 1.6129x; 1.6129x over previous
//
#include <hip/hip_runtime.h>
#include <float.h>
#include <stdint.h>

#define EMB_DIM  300
#define MAX_LEN  128
#define HIDDEN   1000
#define NCLS     5
#define VOCAB_SZ 50000
#define KPAD     640     // 600 padded to 20*32
#define NPAD     1024    // 1000 padded to 8*128

typedef float    f32x4  __attribute__((ext_vector_type(4)));
typedef __bf16   bf16x8 __attribute__((ext_vector_type(8)));
typedef unsigned short ushort8v __attribute__((ext_vector_type(8)));

__device__ __forceinline__ unsigned short f2bf(float f) {
    union { float f; uint32_t u; } v; v.f = f;
    uint32_t u = v.u;
    return (unsigned short)((u + 0x7FFFu + ((u >> 16) & 1u)) >> 16);   // RNE
}
__device__ __forceinline__ float bf2f(unsigned short h) {
    union { uint32_t u; float f; } v; v.u = ((uint32_t)h) << 16;
    return v.f;
}

// ---------------------------------------------------------------------------
// Kernel A: transpose+convert W1 [600][1000] f32 -> W1T [1024][640] bf16
// (n-major so GEMM B-fragments read contiguous k). Pads with zeros.
// ---------------------------------------------------------------------------
__global__ __launch_bounds__(256) void transpose_w1(
    const float* __restrict__ W1, unsigned short* __restrict__ Bt)
{
    __shared__ float t[32][33];
    const int tx = threadIdx.x & 31, ty = threadIdx.x >> 5;   // 32 x 8
    const int n0 = blockIdx.x * 32, k0 = blockIdx.y * 32;
    #pragma unroll
    for (int i = 0; i < 4; ++i) {
        int k = k0 + ty + i * 8, n = n0 + tx;
        t[ty + i * 8][tx] = (k < 600 && n < HIDDEN) ? W1[(size_t)k * HIDDEN + n] : 0.f;
    }
    __syncthreads();
    #pragma unroll
    for (int i = 0; i < 4; ++i) {
        int n = n0 + ty + i * 8, k = k0 + tx;      // n<1024, k<640 by grid
        Bt[(size_t)n * KPAD + k] = f2bf(t[tx][ty + i * 8]);
    }
}

// ---------------------------------------------------------------------------
// Kernel B: gather + masked avg/max pool -> rep bf16 [B][640] (zero-padded).
// One block (128 thr) per row; lanes 0..74 each own a float4 (4 dims).
// ---------------------------------------------------------------------------
__global__ __launch_bounds__(128) void pool_kernel(
    const int* __restrict__ x, const int* __restrict__ lengths,
    const float* __restrict__ emb, unsigned short* __restrict__ rep)
{
    const int b = blockIdx.x;
    const int t = threadIdx.x;

    __shared__ int sidx[MAX_LEN];
    sidx[t] = x[b * MAX_LEN + t];
    __syncthreads();

    unsigned short* rb = rep + (size_t)b * KPAD;

    if (t >= 75) {
        if (t < 85) {                      // zero pad cols 600..639
            ushort4 z = {0, 0, 0, 0};
            *(ushort4*)(rb + 600 + (t - 75) * 4) = z;
        }
        return;
    }

    int L = lengths[b];
    L = max(1, min(L, MAX_LEN));

    const int d = t * 4;
    float4 s  = {0.f, 0.f, 0.f, 0.f};
    float4 mx = {-FLT_MAX, -FLT_MAX, -FLT_MAX, -FLT_MAX};

    for (int i = 0; i < L; ++i) {
        int idx = sidx[i];
        idx = max(0, min(idx, VOCAB_SZ - 1));
        const float4 v = *(const float4*)(emb + (size_t)idx * EMB_DIM + d);
        s.x += v.x; s.y += v.y; s.z += v.z; s.w += v.w;
        mx.x = fmaxf(mx.x, v.x); mx.y = fmaxf(mx.y, v.y);
        mx.z = fmaxf(mx.z, v.z); mx.w = fmaxf(mx.w, v.w);
    }

    const float inv = 1.0f / (float)L;
    ushort4 av, mv;
    av.x = f2bf(s.x * inv); av.y = f2bf(s.y * inv);
    av.z = f2bf(s.z * inv); av.w = f2bf(s.w * inv);
    mv.x = f2bf(mx.x); mv.y = f2bf(mx.y); mv.z = f2bf(mx.z); mv.w = f2bf(mx.w);
    *(ushort4*)(rb + d)       = av;     // avg -> cols [0,300)
    *(ushort4*)(rb + 300 + d) = mv;     // max -> cols [300,600)
}

// ---------------------------------------------------------------------------
// Kernel C: hidden = relu(rep @ W1 + b1) via bf16 MFMA 16x16x32.
// Tile 128(M) x 64(N), BK=32, 256 thr = 4 waves (2x2), wave tile 64x32.
// Double-buffered LDS staged with global_load_lds (16B).
// ---------------------------------------------------------------------------
#define BM 128
#define BN 64
#define BK 32

__global__ __launch_bounds__(256, 2) void gemm1_mfma(
    const unsigned short* __restrict__ A,    // rep  [M][640] bf16
    const unsigned short* __restrict__ Bt,   // W1T  [1024][640] bf16
    const float* __restrict__ bias,          // [1000] f32
    unsigned short* __restrict__ H,          // hidden [M][1000] bf16
    int M)
{
    __shared__ unsigned short As[2][BM * BK];   // 8 KB each
    __shared__ unsigned short Bs[2][BN * BK];   // 4 KB each

    const int tid  = threadIdx.x;
    const int wv   = tid >> 6;
    const int lane = tid & 63;
    const int bm   = blockIdx.y * BM;
    const int bn   = blockIdx.x * BN;
    const int wr   = (wv & 1) * 64;    // wave row offset in tile
    const int wc   = (wv >> 1) * 32;   // wave col offset in tile

    f32x4 acc[4][2] = {};

    auto stage = [&](int buf, int k0) {
        // A tile: 128 rows x 64 B. 8 wave-instrs total (2/wave), 16 rows each.
        #pragma unroll
        for (int j = 0; j < 2; ++j) {
            int ci  = (wv * 2 + j) * 64 + lane;          // 16B-chunk id
            int row = ci >> 2, c = ci & 3;
            const unsigned short* g = A + (size_t)(bm + row) * KPAD + k0 + c * 8;
            unsigned short* l = &As[buf][(wv * 2 + j) * 512];  // wave-uniform
            __builtin_amdgcn_global_load_lds(g, l, 16, 0, 0);
        }
        // B tile: 64 rows x 64 B. 4 wave-instrs (1/wave).
        {
            int ci  = wv * 64 + lane;
            int row = ci >> 2, c = ci & 3;
            const unsigned short* g = Bt + (size_t)(bn + row) * KPAD + k0 + c * 8;
            unsigned short* l = &Bs[buf][wv * 512];
            __builtin_amdgcn_global_load_lds(g, l, 16, 0, 0);
        }
    };

    stage(0, 0);
    int cur = 0;
    const int q = lane >> 4, r16 = lane & 15;

    for (int it = 0; it < KPAD / BK; ++it) {
        __syncthreads();                       // publishes buf `cur`
        if (it + 1 < KPAD / BK) stage(cur ^ 1, (it + 1) * BK);

        bf16x8 af[4], bfr[2];
        #pragma unroll
        for (int mi = 0; mi < 4; ++mi) {
            int row = wr + mi * 16 + r16;
            af[mi] = *(const bf16x8*)&As[cur][row * BK + q * 8];
        }
        #pragma unroll
        for (int nj = 0; nj < 2; ++nj) {
            int row = wc + nj * 16 + r16;
            bfr[nj] = *(const bf16x8*)&Bs[cur][row * BK + q * 8];
        }
        #pragma unroll
        for (int mi = 0; mi < 4; ++mi)
            #pragma unroll
            for (int nj = 0; nj < 2; ++nj)
                acc[mi][nj] = __builtin_amdgcn_mfma_f32_16x16x32_bf16(
                    af[mi], bfr[nj], acc[mi][nj], 0, 0, 0);
        cur ^= 1;
    }

    // Epilogue. C/D layout: col = lane&15, row = (lane>>4)*4 + reg.
    #pragma unroll
    for (int nj = 0; nj < 2; ++nj) {
        int n = bn + wc + nj * 16 + r16;
        if (n >= HIDDEN) continue;
        float bv = bias[n];
        #pragma unroll
        for (int mi = 0; mi < 4; ++mi) {
            #pragma unroll
            for (int r = 0; r < 4; ++r) {
                int m = bm + wr + mi * 16 + q * 4 + r;
                float v = acc[mi][nj][r] + bv;
                H[(size_t)m * HIDDEN + n] = f2bf(fmaxf(v, 0.f));
            }
        }
    }
}

// ---------------------------------------------------------------------------
// Kernel D: logits = hidden @ W2 + b2. One wave per row, bf16x8 loads.
// Lane covers k = {lane*8..+8} and {512+lane*8..+8} (exactly 1000 total).
// ---------------------------------------------------------------------------
__global__ __launch_bounds__(64) void gemm2_kernel(
    const unsigned short* __restrict__ Hb,   // [B][1000] bf16
    const float* __restrict__ W2,            // [1000][5]
    const float* __restrict__ b2,            // [5]
    float* __restrict__ out)                 // [B][5]
{
    const int b = blockIdx.x, lane = threadIdx.x;
    const unsigned short* hr = Hb + (size_t)b * HIDDEN;

    float acc[NCLS] = {0.f, 0.f, 0.f, 0.f, 0.f};
    #pragma unroll
    for (int c = 0; c < 2; ++c) {
        int k0 = c * 512 + lane * 8;
        if (k0 < HIDDEN) {
            ushort8v hv = *(const ushort8v*)(hr + k0);
            #pragma unroll
            for (int j = 0; j < 8; ++j) {
                float h = bf2f(hv[j]);
                const float* w = W2 + (size_t)(k0 + j) * NCLS;
                #pragma unroll
                for (int cc = 0; cc < NCLS; ++cc) acc[cc] += h * w[cc];
            }
        }
    }
    #pragma unroll
    for (int off = 32; off > 0; off >>= 1)
        #pragma unroll
        for (int cc = 0; cc < NCLS; ++cc)
            acc[cc] += __shfl_down(acc[cc], off, 64);

    if (lane == 0) {
        #pragma unroll
        for (int cc = 0; cc < NCLS; ++cc)
            out[(size_t)b * NCLS + cc] = acc[cc] + b2[cc];
    }
}

// ---------------------------------------------------------------------------
extern "C" void kernel_launch(void* const* d_in, const int* in_sizes, int n_in,
                              void* d_out, int out_size, void* d_ws, size_t ws_size,
                              hipStream_t stream)
{
    const int*   x       = (const int*)d_in[0];
    const int*   lengths = (const int*)d_in[1];
    const float* emb     = (const float*)d_in[2];
    const float* W1      = (const float*)d_in[3];
    const float* b1      = (const float*)d_in[4];
    const float* W2      = (const float*)d_in[5];
    const float* b2      = (const float*)d_in[6];
    float*       out     = (float*)d_out;

    const int B = in_sizes[1];               // 4096

    unsigned short* rep    = (unsigned short*)d_ws;                 // [B][640]
    unsigned short* w1t    = rep + (size_t)B * KPAD;                // [1024][640]
    unsigned short* hidden = w1t + (size_t)NPAD * KPAD;             // [B][1000]

    transpose_w1<<<dim3(32, 20), 256, 0, stream>>>(W1, w1t);
    pool_kernel<<<B, 128, 0, stream>>>(x, lengths, emb, rep);

    dim3 g1(NPAD / BN, B / BM);              // (16, 32)
    gemm1_mfma<<<g1, 256, 0, stream>>>(rep, w1t, b1, hidden, B);

    gemm2_kernel<<<B, 64, 0, stream>>>(hidden, W2, b2, out);
}